// Round 13
// baseline (39.839 us; speedup 1.0000x reference)
//
#include <hip/hip_runtime.h>
#include <cmath>

constexpr int NN   = 1536;      // nodes
constexpr int FF   = 512;       // in features
constexpr int HH   = 64;        // hidden
constexpr int RPB  = 16;        // rows per block
constexpr int NB   = NN / RPB;  // 96 blocks, 1/CU (LDS-limited), all co-resident
constexpr int NT   = 1024;      // 16 waves
constexpr int KST  = NN / 32;   // 48 k-steps
constexpr int KST1 = FF / 32;   // 16 k-steps for x@W1

// LDS byte offsets (manual union)
constexpr int O_STG  = 0;       //  98304: layer staging [16 waves][6144]
constexpr int O_AL   = 0;       //  16384: pre: x A-tiles
constexpr int O_BL   = 16384;   //  65536: pre: W1 B-tiles
constexpr int O_RED  = 98304;   //  34816: [8][4][16][17] f32 (pre uses [4][4][16][17])
constexpr int O_WNB  = 133120;  //  16384: epilogue W B-tiles (16 x 512 u16)
constexpr int O_XA   = 149504;  //   2048: u16 scratch (t1 rows / x A-tiles)
constexpr int O_XLOC = 151552;  //   4160: [16][65] f32
constexpr int O_ANX  = 155712;  //   4160: [16][65] f32
constexpr int O_DEG  = 159872;  //     64: degs[16]
constexpr int LDS_SZ = 159936;  // 156.2 KB -> 1 block/CU

using f32x4  = __attribute__((ext_vector_type(4))) float;
using bf16x8 = __attribute__((ext_vector_type(8))) short;
typedef unsigned short u16;
typedef unsigned long long u64;

__device__ __forceinline__ u16 f2bf(float f) {  // RNE fp32 -> bf16
  unsigned u = __builtin_bit_cast(unsigned, f);
  return (u16)((u + 0x7fffu + ((u >> 16) & 1u)) >> 16);
}

// B-tile index for a [1536 k x 64 c] matrix, column-half contiguous:
// half (c>>5) spans 96KB; within it, tile = (k>>5)*2 + ((c>>4)&1).
__device__ __forceinline__ size_t bidx(int k, int c) {
  return (size_t)((c >> 5) * (KST * 2) + (k >> 5) * 2 + ((c >> 4) & 1)) * 512 +
         ((k & 31) >> 3) * 128 + (c & 15) * 8 + (k & 7);
}

struct Params {
  const float *x, *adj, *W1, *b1, *W2, *b2, *W3, *b3;
  u16 *t1T, *B2T, *B3T;
  float* out;
  unsigned* bar;
};

// Barrier with ZERO cache maintenance: all cross-block data moves via
// agent-scope atomics (complete/read at the coherent point), so arrive and
// poll are RELAXED. __syncthreads drains vmcnt (compiler emits full waitcnt
// before s_barrier), so data stores are IC-complete before the arrive.
__device__ __forceinline__ void gbar2(unsigned* c, unsigned target) {
  __syncthreads();
  if (threadIdx.x == 0) {
    __hip_atomic_fetch_add(c, 1u, __ATOMIC_RELAXED, __HIP_MEMORY_SCOPE_AGENT);
    while (__hip_atomic_load(c, __ATOMIC_RELAXED, __HIP_MEMORY_SCOPE_AGENT) <
           target)
      __builtin_amdgcn_s_sleep(4);
  }
  __syncthreads();
}

__device__ __forceinline__ void pack_wnb(u16* WnB, const float* Wsrc, int tid) {
  // Bmat[k][j'], k 0..63, j' 0..127; j'<64 -> Wn[k][j'], else Wn[64+k][j'-64]
  int jp = tid & 127, kb = (tid >> 7) * 8;
  int srow0 = (jp >> 6) * 64, col = jp & 63;
#pragma unroll
  for (int i = 0; i < 8; ++i) {
    int k = kb + i;
    WnB[((k >> 5) * 8 + (jp >> 4)) * 512 + ((k & 31) >> 3) * 128 +
        (jp & 15) * 8 + (k & 7)] = f2bf(Wsrc[(size_t)(srow0 + k) * HH + col]);
  }
}

__global__ __launch_bounds__(NT, 4) void gcn_f2(Params p) {
  __shared__ __attribute__((aligned(16))) char LB[LDS_SZ];
  u16*   WnB  = (u16*)(LB + O_WNB);
  u16*   xAu  = (u16*)(LB + O_XA);
  float* red  = (float*)(LB + O_RED);
  float* xloc = (float*)(LB + O_XLOC);
  float* anx  = (float*)(LB + O_ANX);
  float* degs = (float*)(LB + O_DEG);

  const int tid = threadIdx.x, lane = tid & 63, wave = tid >> 6;
  const int i0 = blockIdx.x * RPB;

  if (tid < RPB) degs[tid] = 0.f;

  // ---- pre: x rows -> Al tiles (wave = row, lane: 8 k) ----
  {
    int j0 = lane * 8;
    const float4* src = (const float4*)(p.x + (size_t)(i0 + wave) * FF + j0);
    float4 f0 = src[0], f1 = src[1];
    bf16x8 v;
    v[0] = (short)f2bf(f0.x); v[1] = (short)f2bf(f0.y);
    v[2] = (short)f2bf(f0.z); v[3] = (short)f2bf(f0.w);
    v[4] = (short)f2bf(f1.x); v[5] = (short)f2bf(f1.y);
    v[6] = (short)f2bf(f1.z); v[7] = (short)f2bf(f1.w);
    *(bf16x8*)&((u16*)(LB + O_AL))[(j0 >> 5) * 512 + ((j0 & 31) >> 3) * 128 +
                                   wave * 8] = v;
  }
  // ---- pre: W1 -> Bl tiles (thread: one k-row, 32 cols) ----
  {
    u16* Bl = (u16*)(LB + O_BL);
    int k = tid >> 1, c0 = (tid & 1) * 32;
    const float4* src = (const float4*)(p.W1 + (size_t)k * HH + c0);
    int base = (k >> 5) * 2048 + ((k & 31) >> 3) * 128 + (k & 7);
#pragma unroll
    for (int g = 0; g < 8; ++g) {
      float4 f = src[g];
      int c = c0 + g * 4;
      int off = base + (c >> 4) * 512 + (c & 15) * 8;
      Bl[off]      = f2bf(f.x);
      Bl[off + 8]  = f2bf(f.y);
      Bl[off + 16] = f2bf(f.z);
      Bl[off + 24] = f2bf(f.w);
    }
  }
  // ---- adj A-fragments straight from global (kept in VGPRs all layers),
  //      deg partials fused into the same pass ----
  bf16x8 afr[3];
  float dpart = 0.f;
#pragma unroll
  for (int s = 0; s < 3; ++s) {
    const float4* ap =
        (const float4*)(p.adj + (size_t)(i0 + (lane & 15)) * NN +
                        (wave * 3 + s) * 32 + (lane >> 4) * 8);
    float4 f0 = ap[0], f1 = ap[1];
    dpart += f0.x + f0.y + f0.z + f0.w + f1.x + f1.y + f1.z + f1.w;
    bf16x8 v;
    v[0] = (short)f2bf(f0.x); v[1] = (short)f2bf(f0.y);
    v[2] = (short)f2bf(f0.z); v[3] = (short)f2bf(f0.w);
    v[4] = (short)f2bf(f1.x); v[5] = (short)f2bf(f1.y);
    v[6] = (short)f2bf(f1.z); v[7] = (short)f2bf(f1.w);
    afr[s] = v;
  }
  dpart += __shfl_xor(dpart, 16, 64);
  dpart += __shfl_xor(dpart, 32, 64);  // lanes 0-15: row sums for this wave's k
  __syncthreads();
  if (lane < 16) atomicAdd(&degs[lane], dpart);

  // ---- t1 = x @ W1 (MFMA; wave = (ks, cg)) ----
  {
    int ks = wave >> 2, cg = wave & 3;
    f32x4 acc = {0.f, 0.f, 0.f, 0.f};
#pragma unroll
    for (int s = 0; s < 4; ++s) {
      int t = ks * 4 + s;
      bf16x8 a = *(const bf16x8*)&((u16*)(LB + O_AL))[t * 512 + lane * 8];
      bf16x8 b =
          *(const bf16x8*)&((u16*)(LB + O_BL))[(t * 4 + cg) * 512 + lane * 8];
      acc = __builtin_amdgcn_mfma_f32_16x16x32_bf16(a, b, acc, 0, 0, 0);
    }
#pragma unroll
    for (int q = 0; q < 4; ++q)
      red[((ks * 4 + cg) * 16 + ((lane >> 4) * 4 + q)) * 17 + (lane & 15)] =
          acc[q];
  }
  __syncthreads();
  {  // combine 4 k-segments -> bf16 staging in LDS
    int r = wave, c = lane;
    float v = 0.f;
#pragma unroll
    for (int k2 = 0; k2 < 4; ++k2)
      v += red[((k2 * 4 + (c >> 4)) * 16 + r) * 17 + (c & 15)];
    xAu[r * 64 + c] = f2bf(v);
  }
  __syncthreads();
  if (tid < 512) {  // t1T via agent-scope atomic u32 stores (row pairs)
    int rp = (tid >> 6) * 2, c = tid & 63;
    unsigned val =
        (unsigned)xAu[rp * 64 + c] | ((unsigned)xAu[(rp + 1) * 64 + c] << 16);
    __hip_atomic_store((unsigned*)&p.t1T[bidx(i0 + rp, c)], val,
                       __ATOMIC_RELAXED, __HIP_MEMORY_SCOPE_AGENT);
  }
  pack_wnb(WnB, p.W2, tid);
  gbar2(p.bar, NB);

  // ---- layers 0..2 ----
#pragma unroll 1
  for (int l = 0; l < 3; ++l) {
    const u16* TT    = l == 0 ? p.t1T : (l == 1 ? p.B2T : p.B3T);
    const float* bia = l == 0 ? p.b1 : (l == 1 ? p.b2 : p.b3);
    u16* Bout        = l == 0 ? p.B2T : p.B3T;

    f32x4 acc[4] = {};
#pragma unroll
    for (int h = 0; h < 2; ++h) {
      // stage this wave's 6KB of column-half h: agent atomic u64 loads
      // (read the coherent point -- no cache inv needed) + ds_write
      {
        u64* gs = (u64*)((const char*)TT + (size_t)h * 98304 + wave * 6144);
        u64* ld = (u64*)(LB + O_STG + wave * 6144);
        u64 v[12];
#pragma unroll
        for (int j = 0; j < 12; ++j)
          v[j] = __hip_atomic_load(&gs[j * 64 + lane], __ATOMIC_RELAXED,
                                   __HIP_MEMORY_SCOPE_AGENT);
#pragma unroll
        for (int j = 0; j < 12; ++j) ld[j * 64 + lane] = v[j];
      }
      asm volatile("s_waitcnt lgkmcnt(0)" ::: "memory");
      __builtin_amdgcn_sched_barrier(0);
#pragma unroll
      for (int s = 0; s < 3; ++s)
#pragma unroll
        for (int chi = 0; chi < 2; ++chi) {
          bf16x8 b = *(const bf16x8*)(LB + O_STG + wave * 6144 +
                                      (s * 2 + chi) * 1024 + lane * 16);
          acc[h * 2 + chi] = __builtin_amdgcn_mfma_f32_16x16x32_bf16(
              afr[s], b, acc[h * 2 + chi], 0, 0, 0);
        }
    }

    // 8-wave reduction tree (padded stride 17)
    if (wave < 8) {
#pragma unroll
      for (int cg = 0; cg < 4; ++cg)
#pragma unroll
        for (int q = 0; q < 4; ++q)
          red[((wave * 4 + cg) * 16 + ((lane >> 4) * 4 + q)) * 17 +
              (lane & 15)] = acc[cg][q];
    }
    __syncthreads();
    if (wave >= 8) {
#pragma unroll
      for (int cg = 0; cg < 4; ++cg)
#pragma unroll
        for (int q = 0; q < 4; ++q)
          red[(((wave - 8) * 4 + cg) * 16 + ((lane >> 4) * 4 + q)) * 17 +
              (lane & 15)] += acc[cg][q];
    }
    __syncthreads();

    {  // combine 8 segments + bias + deg term + activation
      float v = bia[lane];
#pragma unroll
      for (int s = 0; s < 8; ++s)
        v += red[((s * 4 + (lane >> 4)) * 16 + wave) * 17 + (lane & 15)];
      if (l >= 1) v += anx[wave * 65 + lane] * degs[wave];
      if (l == 0) v = fmaxf(v, 0.f);
      if (l == 1) v = v > 0.f ? v : expm1f(v);
      xloc[wave * 65 + lane] = v;
      if (l < 2)
        xAu[(lane >> 5) * 512 + ((lane & 31) >> 3) * 128 + wave * 8 +
            (lane & 7)] = f2bf(v);
    }
    __syncthreads();

    if (l < 2) {
      // epilogue: [anx | Bout] = x @ [Wn_top | Wn_bot] via MFMA (8 waves)
      if (wave < 8) {
        f32x4 a2 = {};
#pragma unroll
        for (int s = 0; s < 2; ++s) {
          bf16x8 a = *(const bf16x8*)&xAu[s * 512 + lane * 8];
          bf16x8 b = *(const bf16x8*)&WnB[(s * 8 + wave) * 512 + lane * 8];
          a2 = __builtin_amdgcn_mfma_f32_16x16x32_bf16(a, b, a2, 0, 0, 0);
        }
        int row = (lane >> 4) * 4, colg = lane & 15;
        if (wave < 4) {
          int c = wave * 16 + colg;
#pragma unroll
          for (int q = 0; q < 4; ++q) anx[(row + q) * 65 + c] = a2[q];
        } else {
          int c = (wave - 4) * 16 + colg;
          u64 val = 0;
#pragma unroll
          for (int q = 0; q < 4; ++q) val |= (u64)f2bf(a2[q]) << (16 * q);
          __hip_atomic_store((u64*)&Bout[bidx(i0 + row, c)], val,
                             __ATOMIC_RELAXED, __HIP_MEMORY_SCOPE_AGENT);
        }
      }
      __syncthreads();
      if (l == 0) pack_wnb(WnB, p.W3, tid);
      gbar2(p.bar, (unsigned)((2 + l) * NB));
    } else {
      // log_softmax: wave = row (normal stores; kernel-end flush suffices)
      float v = xloc[wave * 65 + lane];
      float m = v;
#pragma unroll
      for (int off = 32; off; off >>= 1) m = fmaxf(m, __shfl_xor(m, off, 64));
      float e = expf(v - m);
      float ssum = e;
#pragma unroll
      for (int off = 32; off; off >>= 1) ssum += __shfl_xor(ssum, off, 64);
      p.out[(size_t)(i0 + wave) * HH + lane] = v - m - logf(ssum);
    }
  }
}

extern "C" void kernel_launch(void* const* d_in, const int* in_sizes, int n_in,
                              void* d_out, int out_size, void* d_ws,
                              size_t ws_size, hipStream_t stream) {
  Params p;
  p.x   = (const float*)d_in[0];
  p.adj = (const float*)d_in[2];  // adj1; d_in[1]/d_in[3] are dead inputs
  p.W1  = (const float*)d_in[4];
  p.b1  = (const float*)d_in[5];
  p.W2  = (const float*)d_in[6];
  p.b2  = (const float*)d_in[7];
  p.W3  = (const float*)d_in[8];
  p.b3  = (const float*)d_in[9];
  p.out = (float*)d_out;

  char* ws = (char*)d_ws;
  p.t1T = (u16*)ws;                  // 196,608 B each (2 x 96KB halves)
  p.B2T = (u16*)(ws + 196608);
  p.B3T = (u16*)(ws + 393216);
  p.bar = (unsigned*)(ws + 589824);

  // barrier counter must start at 0 every call
  hipMemsetAsync((void*)p.bar, 0, 128, stream);
  gcn_f2<<<NB, NT, 0, stream>>>(p);
}

// Round 14
// 36.398 us; speedup vs baseline: 1.0945x; 1.0945x over previous
//
#include <hip/hip_runtime.h>
#include <cmath>

constexpr int NN   = 1536;      // nodes
constexpr int FF   = 512;       // in features
constexpr int HH   = 64;        // hidden
constexpr int RPB  = 16;        // rows per block
constexpr int NB   = NN / RPB;  // 96 blocks, 1/CU, co-resident
constexpr int NT   = 1024;      // 16 waves
constexpr int KST  = NN / 32;   // 48 k-steps

// gcn_3l LDS offsets (bytes)
constexpr int O_STG  = 0;       //  98304: staging [16 waves][6144]
constexpr int O_RED  = 98304;   //  34816: [8][4][16][17] f32
constexpr int O_WNB  = 133120;  //  16384: epilogue W B-tiles
constexpr int O_XA   = 149504;  //   2048: x A-tiles [2][512] u16
constexpr int O_XLOC = 151552;  //   4160: [16][65] f32
constexpr int O_ANX  = 155712;  //   4160: [16][65] f32
constexpr int O_DEG  = 159872;  //     64
constexpr int LDS_SZ = 159936;  // 156.2 KB

using f32x4  = __attribute__((ext_vector_type(4))) float;
using bf16x8 = __attribute__((ext_vector_type(8))) short;
typedef unsigned short u16;
typedef unsigned long long u64;

__device__ __forceinline__ u16 f2bf(float f) {  // RNE fp32 -> bf16
  unsigned u = __builtin_bit_cast(unsigned, f);
  return (u16)((u + 0x7fffu + ((u >> 16) & 1u)) >> 16);
}

__device__ __forceinline__ size_t bidx(int k, int c) {
  return (size_t)((c >> 5) * (KST * 2) + (k >> 5) * 2 + ((c >> 4) & 1)) * 512 +
         ((k & 31) >> 3) * 128 + (c & 15) * 8 + (k & 7);
}

__device__ __forceinline__ void gl_lds16(const void* g, void* l) {
  __builtin_amdgcn_global_load_lds(
      (const __attribute__((address_space(1))) unsigned*)g,
      (__attribute__((address_space(3))) unsigned*)l, 16, 0, 0);
}

struct Params {
  const float *x, *adj, *W1, *b1, *W2, *b2, *W3, *b3;
  u16 *t1T, *B2T, *B3T;
  float* out;
  unsigned* bar;
};

// Two-level relaxed barrier: 12 arrivals per sub-line (8 lines), leaders
// (blockIdx<8) aggregate into one root line (8 RMWs), then broadcast DONE
// on their sub-line. No acquire/release: cross-block data moves via
// agent-atomic stores (IC write-through) + cold-line cacheable reads.
__device__ __forceinline__ void gbar3(unsigned* bar, int slot) {
  __syncthreads();  // drains vmcnt(0): all atomic stores IC-complete
  if (threadIdx.x == 0) {
    const unsigned g = blockIdx.x & 7u;
    unsigned* sub  = bar + ((unsigned)slot * 9 + g) * 16;
    unsigned* root = bar + ((unsigned)slot * 9 + 8) * 16;
    if (blockIdx.x < 8) {
      __hip_atomic_fetch_add(sub, 1u, __ATOMIC_RELAXED, __HIP_MEMORY_SCOPE_AGENT);
      while (__hip_atomic_load(sub, __ATOMIC_RELAXED, __HIP_MEMORY_SCOPE_AGENT) < 12u)
        __builtin_amdgcn_s_sleep(1);
      __hip_atomic_fetch_add(root, 1u, __ATOMIC_RELAXED, __HIP_MEMORY_SCOPE_AGENT);
      while (__hip_atomic_load(root, __ATOMIC_RELAXED, __HIP_MEMORY_SCOPE_AGENT) < 8u)
        __builtin_amdgcn_s_sleep(1);
      __hip_atomic_fetch_add(sub, 1u << 16, __ATOMIC_RELAXED, __HIP_MEMORY_SCOPE_AGENT);
    } else {
      __hip_atomic_fetch_add(sub, 1u, __ATOMIC_RELAXED, __HIP_MEMORY_SCOPE_AGENT);
      while (__hip_atomic_load(sub, __ATOMIC_RELAXED, __HIP_MEMORY_SCOPE_AGENT) <
             (1u << 16))
        __builtin_amdgcn_s_sleep(1);
    }
  }
  __syncthreads();
}

__device__ __forceinline__ void pack_wnb(u16* WnB, const float* Wsrc, int tid) {
  int jp = tid & 127, kb = (tid >> 7) * 8;
  int srow0 = (jp >> 6) * 64, col = jp & 63;
#pragma unroll
  for (int i = 0; i < 8; ++i) {
    int k = kb + i;
    WnB[((k >> 5) * 8 + (jp >> 4)) * 512 + ((k & 31) >> 3) * 128 +
        (jp & 15) * 8 + (k & 7)] = f2bf(Wsrc[(size_t)(srow0 + k) * HH + col]);
  }
}

// ---- kernel A: t1 = x @ W1 -> t1T (normal stores; boundary = visibility) ----
__global__ __launch_bounds__(NT, 4) void k_t1(const float* __restrict__ x,
                                              const float* __restrict__ W1,
                                              u16* __restrict__ t1T) {
  __shared__ u16 Al[16 * 512];              // 16 KB
  __shared__ u16 Bl[16 * 4 * 512];          // 64 KB
  __shared__ float red0[4][4][16][17];      // 17.4 KB
  const int tid = threadIdx.x, lane = tid & 63, wave = tid >> 6;
  const int i0 = blockIdx.x * RPB;

  {  // x rows -> Al (wave = row, lane: 8 k)
    int j0 = lane * 8;
    const float4* src = (const float4*)(x + (size_t)(i0 + wave) * FF + j0);
    float4 f0 = src[0], f1 = src[1];
    bf16x8 v;
    v[0] = (short)f2bf(f0.x); v[1] = (short)f2bf(f0.y);
    v[2] = (short)f2bf(f0.z); v[3] = (short)f2bf(f0.w);
    v[4] = (short)f2bf(f1.x); v[5] = (short)f2bf(f1.y);
    v[6] = (short)f2bf(f1.z); v[7] = (short)f2bf(f1.w);
    *(bf16x8*)&Al[(j0 >> 5) * 512 + ((j0 & 31) >> 3) * 128 + wave * 8] = v;
  }
  {  // W1 -> Bl (thread: one k-row, 32 cols)
    int k = tid >> 1, c0 = (tid & 1) * 32;
    const float4* src = (const float4*)(W1 + (size_t)k * HH + c0);
    int base = (k >> 5) * 2048 + ((k & 31) >> 3) * 128 + (k & 7);
#pragma unroll
    for (int g = 0; g < 8; ++g) {
      float4 f = src[g];
      int c = c0 + g * 4;
      int off = base + (c >> 4) * 512 + (c & 15) * 8;
      Bl[off]      = f2bf(f.x);
      Bl[off + 8]  = f2bf(f.y);
      Bl[off + 16] = f2bf(f.z);
      Bl[off + 24] = f2bf(f.w);
    }
  }
  __syncthreads();
  {  // MFMA: wave = (ks, cg)
    int ks = wave >> 2, cg = wave & 3;
    f32x4 acc = {0.f, 0.f, 0.f, 0.f};
#pragma unroll
    for (int s = 0; s < 4; ++s) {
      int t = ks * 4 + s;
      bf16x8 a = *(const bf16x8*)&Al[t * 512 + lane * 8];
      bf16x8 b = *(const bf16x8*)&Bl[(t * 4 + cg) * 512 + lane * 8];
      acc = __builtin_amdgcn_mfma_f32_16x16x32_bf16(a, b, acc, 0, 0, 0);
    }
#pragma unroll
    for (int q = 0; q < 4; ++q)
      red0[ks][cg][(lane >> 4) * 4 + q][lane & 15] = acc[q];
  }
  __syncthreads();
  {  // combine 4 k-segments, write t1T
    int r = wave, c = lane;
    float v = red0[0][c >> 4][r][c & 15] + red0[1][c >> 4][r][c & 15] +
              red0[2][c >> 4][r][c & 15] + red0[3][c >> 4][r][c & 15];
    t1T[bidx(i0 + r, c)] = f2bf(v);
  }
}

// ---- kernel B: 3 layers, 2 hierarchical barriers ----
__global__ __launch_bounds__(NT, 4) void gcn_3l(Params p) {
  __shared__ __attribute__((aligned(16))) char LB[LDS_SZ];
  u16*   WnB  = (u16*)(LB + O_WNB);
  u16*   xAu  = (u16*)(LB + O_XA);
  float* red  = (float*)(LB + O_RED);
  float* xloc = (float*)(LB + O_XLOC);
  float* anx  = (float*)(LB + O_ANX);
  float* degs = (float*)(LB + O_DEG);

  const int tid = threadIdx.x, lane = tid & 63, wave = tid >> 6;
  const int i0 = blockIdx.x * RPB;

  if (tid < RPB) degs[tid] = 0.f;

  // adj A-fragments straight from global (VGPRs, all layers) + deg partials
  bf16x8 afr[3];
  float dpart = 0.f;
#pragma unroll
  for (int s = 0; s < 3; ++s) {
    const float4* ap =
        (const float4*)(p.adj + (size_t)(i0 + (lane & 15)) * NN +
                        (wave * 3 + s) * 32 + (lane >> 4) * 8);
    float4 f0 = ap[0], f1 = ap[1];
    dpart += f0.x + f0.y + f0.z + f0.w + f1.x + f1.y + f1.z + f1.w;
    bf16x8 v;
    v[0] = (short)f2bf(f0.x); v[1] = (short)f2bf(f0.y);
    v[2] = (short)f2bf(f0.z); v[3] = (short)f2bf(f0.w);
    v[4] = (short)f2bf(f1.x); v[5] = (short)f2bf(f1.y);
    v[6] = (short)f2bf(f1.z); v[7] = (short)f2bf(f1.w);
    afr[s] = v;
  }
  dpart += __shfl_xor(dpart, 16, 64);
  dpart += __shfl_xor(dpart, 32, 64);
  pack_wnb(WnB, p.W2, tid);
  __syncthreads();
  if (lane < 16) atomicAdd(&degs[lane], dpart);

#pragma unroll 1
  for (int l = 0; l < 3; ++l) {
    const u16* TT    = l == 0 ? p.t1T : (l == 1 ? p.B2T : p.B3T);
    const float* bia = l == 0 ? p.b1 : (l == 1 ? p.b2 : p.b3);
    u16* Bout        = l == 0 ? p.B2T : p.B3T;

    f32x4 acc[4] = {};
#pragma unroll
    for (int h = 0; h < 2; ++h) {
      {  // stage this wave's 6KB of column-half h (cacheable gl_lds)
        const char* gsrc = (const char*)TT + (size_t)h * 98304 + wave * 6144 +
                           (size_t)lane * 16;
        char* ldst = LB + O_STG + wave * 6144;
        asm volatile("s_waitcnt lgkmcnt(0)" ::: "memory");
#pragma unroll
        for (int r = 0; r < 6; ++r) gl_lds16(gsrc + r * 1024, ldst + r * 1024);
      }
      asm volatile("s_waitcnt vmcnt(0)" ::: "memory");
      __builtin_amdgcn_sched_barrier(0);
#pragma unroll
      for (int s = 0; s < 3; ++s)
#pragma unroll
        for (int chi = 0; chi < 2; ++chi) {
          bf16x8 b = *(const bf16x8*)(LB + O_STG + wave * 6144 +
                                      (s * 2 + chi) * 1024 + lane * 16);
          acc[h * 2 + chi] = __builtin_amdgcn_mfma_f32_16x16x32_bf16(
              afr[s], b, acc[h * 2 + chi], 0, 0, 0);
        }
    }

    // 8-wave reduction tree (padded stride 17)
    if (wave < 8) {
#pragma unroll
      for (int cg = 0; cg < 4; ++cg)
#pragma unroll
        for (int q = 0; q < 4; ++q)
          red[((wave * 4 + cg) * 16 + ((lane >> 4) * 4 + q)) * 17 +
              (lane & 15)] = acc[cg][q];
    }
    __syncthreads();
    if (wave >= 8) {
#pragma unroll
      for (int cg = 0; cg < 4; ++cg)
#pragma unroll
        for (int q = 0; q < 4; ++q)
          red[(((wave - 8) * 4 + cg) * 16 + ((lane >> 4) * 4 + q)) * 17 +
              (lane & 15)] += acc[cg][q];
    }
    __syncthreads();

    {  // combine + bias + deg term + activation
      float v = bia[lane];
#pragma unroll
      for (int s = 0; s < 8; ++s)
        v += red[((s * 4 + (lane >> 4)) * 16 + wave) * 17 + (lane & 15)];
      if (l >= 1) v += anx[wave * 65 + lane] * degs[wave];
      if (l == 0) v = fmaxf(v, 0.f);
      if (l == 1) v = v > 0.f ? v : expm1f(v);
      xloc[wave * 65 + lane] = v;
      if (l < 2)
        xAu[(lane >> 5) * 512 + ((lane & 31) >> 3) * 128 + wave * 8 +
            (lane & 7)] = f2bf(v);
    }
    __syncthreads();

    if (l < 2) {
      // epilogue: [anx | Bout] = x @ [Wn_top | Wn_bot] via MFMA (8 waves)
      if (wave < 8) {
        f32x4 a2 = {};
#pragma unroll
        for (int s = 0; s < 2; ++s) {
          bf16x8 a = *(const bf16x8*)&xAu[s * 512 + lane * 8];
          bf16x8 b = *(const bf16x8*)&WnB[(s * 8 + wave) * 512 + lane * 8];
          a2 = __builtin_amdgcn_mfma_f32_16x16x32_bf16(a, b, a2, 0, 0, 0);
        }
        int row = (lane >> 4) * 4, colg = lane & 15;
        if (wave < 4) {
          int c = wave * 16 + colg;
#pragma unroll
          for (int q = 0; q < 4; ++q) anx[(row + q) * 65 + c] = a2[q];
        } else {
          int c = (wave - 4) * 16 + colg;
          u64 val = 0;
#pragma unroll
          for (int q = 0; q < 4; ++q) val |= (u64)f2bf(a2[q]) << (16 * q);
          __hip_atomic_store((u64*)&Bout[bidx(i0 + row, c)], val,
                             __ATOMIC_RELAXED, __HIP_MEMORY_SCOPE_AGENT);
        }
      }
      __syncthreads();
      if (l == 0) pack_wnb(WnB, p.W3, tid);
      gbar3(p.bar, l);
    } else {
      // log_softmax: wave = row
      float v = xloc[wave * 65 + lane];
      float m = v;
#pragma unroll
      for (int off = 32; off; off >>= 1) m = fmaxf(m, __shfl_xor(m, off, 64));
      float e = expf(v - m);
      float ssum = e;
#pragma unroll
      for (int off = 32; off; off >>= 1) ssum += __shfl_xor(ssum, off, 64);
      p.out[(size_t)(i0 + wave) * HH + lane] = v - m - logf(ssum);
    }
  }
}

extern "C" void kernel_launch(void* const* d_in, const int* in_sizes, int n_in,
                              void* d_out, int out_size, void* d_ws,
                              size_t ws_size, hipStream_t stream) {
  Params p;
  p.x   = (const float*)d_in[0];
  p.adj = (const float*)d_in[2];  // adj1; d_in[1]/d_in[3] are dead inputs
  p.W1  = (const float*)d_in[4];
  p.b1  = (const float*)d_in[5];
  p.W2  = (const float*)d_in[6];
  p.b2  = (const float*)d_in[7];
  p.W3  = (const float*)d_in[8];
  p.b3  = (const float*)d_in[9];
  p.out = (float*)d_out;

  char* ws = (char*)d_ws;
  p.t1T = (u16*)ws;                  // 196,608 B each (2 x 96KB halves)
  p.B2T = (u16*)(ws + 196608);
  p.B3T = (u16*)(ws + 393216);
  p.bar = (unsigned*)(ws + 589824);  // 2 slots x 9 lines x 64 B

  hipMemsetAsync((void*)p.bar, 0, 4096, stream);
  k_t1<<<NB, NT, 0, stream>>>(p.x, p.W1, p.t1T);
  gcn_3l<<<NB, NT, 0, stream>>>(p);
}

// Round 15
// 33.961 us; speedup vs baseline: 1.1731x; 1.0717x over previous
//
#include <hip/hip_runtime.h>
#include <cmath>

constexpr int NN   = 1536;      // nodes
constexpr int FF   = 512;       // in features
constexpr int HH   = 64;        // hidden
constexpr int RPB  = 16;        // rows per block
constexpr int NB   = NN / RPB;  // 96 blocks
constexpr int NT   = 1024;      // 16 waves
constexpr int KST  = NN / 32;   // 48 k-steps

using f32x4  = __attribute__((ext_vector_type(4))) float;
using bf16x8 = __attribute__((ext_vector_type(8))) short;
using u16x4  = __attribute__((ext_vector_type(4))) unsigned short;
typedef unsigned short u16;

__device__ __forceinline__ u16 f2bf(float f) {  // RNE fp32 -> bf16
  unsigned u = __builtin_bit_cast(unsigned, f);
  return (u16)((u + 0x7fffu + ((u >> 16) & 1u)) >> 16);
}

// B-tile index for a [1536 k x 64 c] matrix, column-half contiguous:
// half (c>>5) spans 96KB; within it, tile = (k>>5)*2 + ((c>>4)&1).
__device__ __forceinline__ size_t bidx(int k, int c) {
  return (size_t)((c >> 5) * (KST * 2) + (k >> 5) * 2 + ((c >> 4) & 1)) * 512 +
         ((k & 31) >> 3) * 128 + (c & 15) * 8 + (k & 7);
}

__device__ __forceinline__ void gl_lds16(const void* g, void* l) {
  __builtin_amdgcn_global_load_lds(
      (const __attribute__((address_space(1))) unsigned*)g,
      (__attribute__((address_space(3))) unsigned*)l, 16, 0, 0);
}

__device__ __forceinline__ void pack_wnb(u16* WnB, const float* Wsrc, int tid) {
  // Bmat[k][j'], k 0..63, j' 0..127; j'<64 -> Wn[k][j'], else Wn[64+k][j'-64]
  int jp = tid & 127, kb = (tid >> 7) * 8;
  int srow0 = (jp >> 6) * 64, col = jp & 63;
#pragma unroll
  for (int i = 0; i < 8; ++i) {
    int k = kb + i;
    WnB[((k >> 5) * 8 + (jp >> 4)) * 512 + ((k & 31) >> 3) * 128 +
        (jp & 15) * 8 + (k & 7)] = f2bf(Wsrc[(size_t)(srow0 + k) * HH + col]);
  }
}

// ---- k_t1: t1 = x @ W1 -> t1T B-tiles (lean: no adj access) ----
__global__ __launch_bounds__(NT, 4) void k_t1(const float* __restrict__ x,
                                              const float* __restrict__ W1,
                                              u16* __restrict__ t1T) {
  __shared__ u16 Al[16 * 512];          // 16 KB
  __shared__ u16 Bl[16 * 4 * 512];      // 64 KB
  __shared__ float red0[4][4][16][17];  // 17.4 KB
  const int tid = threadIdx.x, lane = tid & 63, wave = tid >> 6;
  const int i0 = blockIdx.x * RPB;

  {  // x rows -> Al (wave = row, lane: 8 k)
    int j0 = lane * 8;
    const float4* src = (const float4*)(x + (size_t)(i0 + wave) * FF + j0);
    float4 f0 = src[0], f1 = src[1];
    bf16x8 v;
    v[0] = (short)f2bf(f0.x); v[1] = (short)f2bf(f0.y);
    v[2] = (short)f2bf(f0.z); v[3] = (short)f2bf(f0.w);
    v[4] = (short)f2bf(f1.x); v[5] = (short)f2bf(f1.y);
    v[6] = (short)f2bf(f1.z); v[7] = (short)f2bf(f1.w);
    *(bf16x8*)&Al[(j0 >> 5) * 512 + ((j0 & 31) >> 3) * 128 + wave * 8] = v;
  }
  {  // W1 -> Bl (thread: one k-row, 32 cols)
    int k = tid >> 1, c0 = (tid & 1) * 32;
    const float4* src = (const float4*)(W1 + (size_t)k * HH + c0);
    int base = (k >> 5) * 2048 + ((k & 31) >> 3) * 128 + (k & 7);
#pragma unroll
    for (int g = 0; g < 8; ++g) {
      float4 f = src[g];
      int c = c0 + g * 4;
      int off = base + (c >> 4) * 512 + (c & 15) * 8;
      Bl[off]      = f2bf(f.x);
      Bl[off + 8]  = f2bf(f.y);
      Bl[off + 16] = f2bf(f.z);
      Bl[off + 24] = f2bf(f.w);
    }
  }
  __syncthreads();
  {  // MFMA: wave = (ks, cg)
    int ks = wave >> 2, cg = wave & 3;
    f32x4 acc = {0.f, 0.f, 0.f, 0.f};
#pragma unroll
    for (int s = 0; s < 4; ++s) {
      int t = ks * 4 + s;
      bf16x8 a = *(const bf16x8*)&Al[t * 512 + lane * 8];
      bf16x8 b = *(const bf16x8*)&Bl[(t * 4 + cg) * 512 + lane * 8];
      acc = __builtin_amdgcn_mfma_f32_16x16x32_bf16(a, b, acc, 0, 0, 0);
    }
#pragma unroll
    for (int q = 0; q < 4; ++q)
      red0[ks][cg][(lane >> 4) * 4 + q][lane & 15] = acc[q];
  }
  __syncthreads();
  {  // combine 4 k-segments, write t1T
    int r = wave, c = lane;
    float v = red0[0][c >> 4][r][c & 15] + red0[1][c >> 4][r][c & 15] +
              red0[2][c >> 4][r][c & 15] + red0[3][c >> 4][r][c & 15];
    t1T[bidx(i0 + r, c)] = f2bf(v);
  }
}

// ---- k_layer: adj straight global->VGPR (no adjT); deg inline; quarter-dbuf T staging ----
// MODE 0: x = relu(y+b);          outA = x@Wn_top (f32), outBT = x@Wn_bot
// MODE 1: x = elu(Ain*deg+y+b);   outA/outBT as above
// MODE 2: x = Ain*deg+y+b;        out = log_softmax(x)
template <int MODE>
__global__ __launch_bounds__(NT, 4) void k_layer(
    const float* __restrict__ adj, const u16* __restrict__ TT,
    const float* __restrict__ Ain, const float* __restrict__ bias,
    const float* __restrict__ Wn, float* __restrict__ outA,
    u16* __restrict__ outBT, float* __restrict__ out) {
  // LDS union (bytes): staging [16 waves][6144] @0, red @98304 (34816),
  // WnB @133120 (16384), xA @149504 (2048), xloc @151552 (4160), degs @155712
  __shared__ __attribute__((aligned(16))) char LB[155776];
  float* red  = (float*)(LB + 98304);   // [8][4][16][17]
  u16*   WnB  = (u16*)(LB + 133120);    // 16 tiles x 512 u16
  u16*   xA   = (u16*)(LB + 149504);    // x as A-tiles [2][512]
  float* xloc = (float*)(LB + 151552);  // [16][65]
  float* degs = (float*)(LB + 155712);  // [16]

  const int tid = threadIdx.x, lane = tid & 63, wave = tid >> 6;
  const int i0 = blockIdx.x * RPB;

  if (MODE >= 1 && tid < RPB) degs[tid] = 0.f;

  // adj A-fragments straight from global fp32 (r14-proven layout):
  // lane -> row (lane&15), k = (wave*3+s)*32 + (lane>>4)*8 .. +8
  bf16x8 afr[3];
  float dpart = 0.f;
#pragma unroll
  for (int s = 0; s < 3; ++s) {
    const float4* ap = (const float4*)(adj + (size_t)(i0 + (lane & 15)) * NN +
                                       (wave * 3 + s) * 32 + (lane >> 4) * 8);
    float4 f0 = ap[0], f1 = ap[1];
    if (MODE >= 1)
      dpart += f0.x + f0.y + f0.z + f0.w + f1.x + f1.y + f1.z + f1.w;
    bf16x8 v;
    v[0] = (short)f2bf(f0.x); v[1] = (short)f2bf(f0.y);
    v[2] = (short)f2bf(f0.z); v[3] = (short)f2bf(f0.w);
    v[4] = (short)f2bf(f1.x); v[5] = (short)f2bf(f1.y);
    v[6] = (short)f2bf(f1.z); v[7] = (short)f2bf(f1.w);
    afr[s] = v;
  }
  if (MODE < 2) pack_wnb(WnB, Wn, tid);
  if (MODE >= 1) {
    dpart += __shfl_xor(dpart, 16, 64);
    dpart += __shfl_xor(dpart, 32, 64);
    __syncthreads();  // degs init done
    if (lane < 16) atomicAdd(&degs[lane], dpart);
  }

  // quarter-dbuf staging of T (per-wave 6 KB region; counted vmcnt)
  char* const regA = LB + wave * 6144;
  char* const regB = regA + 3072;
  const int kb = wave * 3;
  const char* tb = (const char*)TT + (size_t)lane * 16;

  f32x4 acc[4] = {};
#pragma unroll
  for (int s = 0; s < 3; ++s)
    gl_lds16(tb + (size_t)((kb + s) * 2 + 0) * 1024, regA + s * 1024);
#pragma unroll
  for (int s = 0; s < 3; ++s)
    gl_lds16(tb + (size_t)((kb + s) * 2 + 1) * 1024, regB + s * 1024);

#pragma unroll
  for (int cg = 0; cg < 4; ++cg) {
    if (cg < 3) asm volatile("s_waitcnt vmcnt(3)" ::: "memory");
    else        asm volatile("s_waitcnt vmcnt(0)" ::: "memory");
    __builtin_amdgcn_sched_barrier(0);
    char* reg = (cg & 1) ? regB : regA;
    bf16x8 b0 = *(const bf16x8*)(reg);
    bf16x8 b1 = *(const bf16x8*)(reg + 1024);
    bf16x8 b2 = *(const bf16x8*)(reg + 2048);
    asm volatile("s_waitcnt lgkmcnt(0)" ::: "memory");
    __builtin_amdgcn_sched_barrier(0);
    if (cg < 2) {  // refill just-consumed region with quarter cg+2
      int q = cg + 2;
#pragma unroll
      for (int s = 0; s < 3; ++s)
        gl_lds16(tb + (size_t)((q >> 1) * 96 + (kb + s) * 2 + (q & 1)) * 1024,
                 reg + s * 1024);
    }
    acc[cg] = __builtin_amdgcn_mfma_f32_16x16x32_bf16(afr[0], b0, acc[cg], 0, 0, 0);
    acc[cg] = __builtin_amdgcn_mfma_f32_16x16x32_bf16(afr[1], b1, acc[cg], 0, 0, 0);
    acc[cg] = __builtin_amdgcn_mfma_f32_16x16x32_bf16(afr[2], b2, acc[cg], 0, 0, 0);
  }

  // 8-wave reduction tree (padded stride 17)
  if (wave < 8) {
#pragma unroll
    for (int cg = 0; cg < 4; ++cg)
#pragma unroll
      for (int q = 0; q < 4; ++q)
        red[((wave * 4 + cg) * 16 + ((lane >> 4) * 4 + q)) * 17 +
            (lane & 15)] = acc[cg][q];
  }
  __syncthreads();
  if (wave >= 8) {
#pragma unroll
    for (int cg = 0; cg < 4; ++cg)
#pragma unroll
      for (int q = 0; q < 4; ++q)
        red[(((wave - 8) * 4 + cg) * 16 + ((lane >> 4) * 4 + q)) * 17 +
            (lane & 15)] += acc[cg][q];
  }
  __syncthreads();

  {  // combine 8 segments + bias + deg term + activation
    float v = bias[lane];
#pragma unroll
    for (int s = 0; s < 8; ++s)
      v += red[((s * 4 + (lane >> 4)) * 16 + wave) * 17 + (lane & 15)];
    if (MODE >= 1) v += Ain[(size_t)(i0 + wave) * HH + lane] * degs[wave];
    if (MODE == 0) v = fmaxf(v, 0.f);
    if (MODE == 1) v = v > 0.f ? v : expm1f(v);
    xloc[wave * 65 + lane] = v;
    if (MODE < 2)
      xA[(lane >> 5) * 512 + ((lane & 31) >> 3) * 128 + wave * 8 +
         (lane & 7)] = f2bf(v);
  }
  __syncthreads();

  if (MODE < 2) {
    // epilogue: [outA | outBT] = x @ [Wn_top | Wn_bot] via MFMA (8 waves)
    if (wave < 8) {
      f32x4 a2 = {};
#pragma unroll
      for (int s = 0; s < 2; ++s) {
        bf16x8 a = *(const bf16x8*)&xA[s * 512 + lane * 8];
        bf16x8 b = *(const bf16x8*)&WnB[(s * 8 + wave) * 512 + lane * 8];
        a2 = __builtin_amdgcn_mfma_f32_16x16x32_bf16(a, b, a2, 0, 0, 0);
      }
      int row = (lane >> 4) * 4, colg = lane & 15;
      if (wave < 4) {
        int c = wave * 16 + colg;
#pragma unroll
        for (int q = 0; q < 4; ++q)
          outA[(size_t)(i0 + row + q) * HH + c] = a2[q];
      } else {
        int c = (wave - 4) * 16 + colg;
        u16x4 v;
#pragma unroll
        for (int q = 0; q < 4; ++q) v[q] = f2bf(a2[q]);
        *(u16x4*)&outBT[bidx(i0 + row, c)] = v;  // 4 consecutive k slots
      }
    }
  } else {
    // log_softmax: wave = row
    float v = xloc[wave * 65 + lane];
    float m = v;
#pragma unroll
    for (int off = 32; off; off >>= 1) m = fmaxf(m, __shfl_xor(m, off, 64));
    float e = expf(v - m);
    float ssum = e;
#pragma unroll
    for (int off = 32; off; off >>= 1) ssum += __shfl_xor(ssum, off, 64);
    out[(size_t)(i0 + wave) * HH + lane] = v - m - logf(ssum);
  }
}

extern "C" void kernel_launch(void* const* d_in, const int* in_sizes, int n_in,
                              void* d_out, int out_size, void* d_ws,
                              size_t ws_size, hipStream_t stream) {
  const float* x   = (const float*)d_in[0];
  const float* adj = (const float*)d_in[2];  // adj1; d_in[1]/[3] are dead
  const float* W1  = (const float*)d_in[4];
  const float* b1  = (const float*)d_in[5];
  const float* W2  = (const float*)d_in[6];
  const float* b2  = (const float*)d_in[7];
  const float* W3  = (const float*)d_in[8];
  const float* b3  = (const float*)d_in[9];
  float* out = (float*)d_out;

  char* ws = (char*)d_ws;
  u16* t1T  = (u16*)ws;                  // 196,608 B each (2 x 96KB halves)
  u16* B2T  = (u16*)(ws + 196608);
  u16* B3T  = (u16*)(ws + 393216);
  float* A2 = (float*)(ws + 589824);     // 393,216 B each
  float* A3 = (float*)(ws + 983040);

  k_t1<<<NB, NT, 0, stream>>>(x, W1, t1T);
  k_layer<0><<<NB, NT, 0, stream>>>(adj, t1T, nullptr, b1, W2, A2, B2T,
                                    nullptr);
  k_layer<1><<<NB, NT, 0, stream>>>(adj, B2T, A2, b2, W3, A3, B3T, nullptr);
  k_layer<2><<<NB, NT, 0, stream>>>(adj, B3T, A3, b3, nullptr, nullptr,
                                    nullptr, out);
}

// Round 16
// 30.082 us; speedup vs baseline: 1.3243x; 1.1289x over previous
//
#include <hip/hip_runtime.h>
#include <cmath>

constexpr int NN   = 1536;      // nodes
constexpr int FF   = 512;       // in features
constexpr int HH   = 64;        // hidden
constexpr int RPB  = 16;        // rows per block
constexpr int NB   = NN / RPB;  // 96 blocks
constexpr int NT   = 1024;      // 16 waves
constexpr int KST  = NN / 32;   // 48 k-steps
constexpr int KST1 = FF / 32;   // 16 k-steps for x@W1

using f32x4  = __attribute__((ext_vector_type(4))) float;
using bf16x8 = __attribute__((ext_vector_type(8))) short;
using u16x4  = __attribute__((ext_vector_type(4))) unsigned short;
typedef unsigned short u16;

__device__ __forceinline__ u16 f2bf(float f) {  // RNE fp32 -> bf16
  unsigned u = __builtin_bit_cast(unsigned, f);
  return (u16)((u + 0x7fffu + ((u >> 16) & 1u)) >> 16);
}
__device__ __forceinline__ float bf2f(u16 a) {
  return __builtin_bit_cast(float, (unsigned)a << 16);
}

// B-tile index for a [1536 k x 64 c] matrix, column-half contiguous:
// half (c>>5) spans a contiguous 96KB; within it, tile = (k>>5)*2 + ((c>>4)&1).
__device__ __forceinline__ size_t bidx(int k, int c) {
  return (size_t)((c >> 5) * (KST * 2) + (k >> 5) * 2 + ((c >> 4) & 1)) * 512 +
         ((k & 31) >> 3) * 128 + (c & 15) * 8 + (k & 7);
}

__device__ __forceinline__ void gl_lds16(const void* g, void* l) {
  __builtin_amdgcn_global_load_lds(
      (const __attribute__((address_space(1))) unsigned*)g,
      (__attribute__((address_space(3))) unsigned*)l, 16, 0, 0);
}

__device__ __forceinline__ void pack_wnb(u16* WnB, const float* Wsrc, int tid) {
  // Bmat[k][j'], k 0..63, j' 0..127; j'<64 -> Wn[k][j'], else Wn[64+k][j'-64]
  int jp = tid & 127, kb = (tid >> 7) * 8;
  int srow0 = (jp >> 6) * 64, col = jp & 63;
#pragma unroll
  for (int i = 0; i < 8; ++i) {
    int k = kb + i;
    WnB[((k >> 5) * 8 + (jp >> 4)) * 512 + ((k & 31) >> 3) * 128 +
        (jp & 15) * 8 + (k & 7)] = f2bf(Wsrc[(size_t)(srow0 + k) * HH + col]);
  }
}

// ---- k_pre: adj -> adjT A-tiles + deg; t1 = x@W1 (MFMA) -> t1T B-tiles ----
__global__ __launch_bounds__(NT, 4) void k_pre(
    const float* __restrict__ x, const float* __restrict__ adj,
    const float* __restrict__ W1,
    u16* __restrict__ adjT, u16* __restrict__ t1T, float* __restrict__ deg) {
  __shared__ u16 Al[KST1 * 512];        // 16 KB
  __shared__ u16 Bl[KST1 * 4 * 512];    // 64 KB
  __shared__ u16 Jl[KST * 512];         // 48 KB
  __shared__ float red0[4][4][16][16];  // 16 KB
  const int tid = threadIdx.x, lane = tid & 63, wave = tid >> 6;
  const int i0 = blockIdx.x * RPB;

  {  // pack x rows -> Al (wave = row, lane: 8 k) -- float4 loads
    int j0 = lane * 8;
    const float4* src = (const float4*)(x + (size_t)(i0 + wave) * FF + j0);
    float4 f0 = src[0], f1 = src[1];
    bf16x8 v;
    v[0] = (short)f2bf(f0.x); v[1] = (short)f2bf(f0.y);
    v[2] = (short)f2bf(f0.z); v[3] = (short)f2bf(f0.w);
    v[4] = (short)f2bf(f1.x); v[5] = (short)f2bf(f1.y);
    v[6] = (short)f2bf(f1.z); v[7] = (short)f2bf(f1.w);
    *(bf16x8*)&Al[(j0 >> 5) * 512 + ((j0 & 31) >> 3) * 128 + wave * 8] = v;
  }
  {  // pack W1 -> Bl (thread: one k-row, 32 cols) -- float4 loads
    int k = tid >> 1, c0 = (tid & 1) * 32;
    const float4* src = (const float4*)(W1 + (size_t)k * HH + c0);
    int base = (k >> 5) * 2048 + ((k & 31) >> 3) * 128 + (k & 7);
#pragma unroll
    for (int g = 0; g < 8; ++g) {
      float4 f = src[g];
      int c = c0 + g * 4;
      int off = base + (c >> 4) * 512 + (c & 15) * 8;
      Bl[off]      = f2bf(f.x);
      Bl[off + 8]  = f2bf(f.y);
      Bl[off + 16] = f2bf(f.z);
      Bl[off + 24] = f2bf(f.w);
    }
  }
  {  // pack adj slab -> Jl + deg (wave = row, lane: 24 k) -- float4 loads
    int j0 = lane * 24;
    const float4* src = (const float4*)(adj + (size_t)(i0 + wave) * NN + j0);
    float4 f[6];
#pragma unroll
    for (int g = 0; g < 6; ++g) f[g] = src[g];
    float ds = 0.f;
#pragma unroll
    for (int g = 0; g < 6; ++g) ds += f[g].x + f[g].y + f[g].z + f[g].w;
#pragma unroll
    for (int g = 0; g < 3; ++g) {
      bf16x8 v;
      v[0] = (short)f2bf(f[g * 2].x);     v[1] = (short)f2bf(f[g * 2].y);
      v[2] = (short)f2bf(f[g * 2].z);     v[3] = (short)f2bf(f[g * 2].w);
      v[4] = (short)f2bf(f[g * 2 + 1].x); v[5] = (short)f2bf(f[g * 2 + 1].y);
      v[6] = (short)f2bf(f[g * 2 + 1].z); v[7] = (short)f2bf(f[g * 2 + 1].w);
      int k = j0 + g * 8;
      *(bf16x8*)&Jl[(k >> 5) * 512 + ((k & 31) >> 3) * 128 + wave * 8] = v;
    }
#pragma unroll
    for (int off = 32; off; off >>= 1) ds += __shfl_xor(ds, off, 64);
    if (lane == 0) deg[i0 + wave] = ds;
  }
  __syncthreads();

  {  // Jl -> adjT (48 KB linear)
    const float4* srcv = (const float4*)Jl;
    float4* dstv = (float4*)(adjT + (size_t)blockIdx.x * KST * 512);
#pragma unroll
    for (int s = 0; s < 3; ++s) dstv[tid + s * NT] = srcv[tid + s * NT];
  }
  {  // MFMA: t1 = x @ W1. wave = (ks 0..3, cg 0..3)
    int ks = wave >> 2, cg = wave & 3;
    f32x4 acc = {0.f, 0.f, 0.f, 0.f};
#pragma unroll
    for (int s = 0; s < 4; ++s) {
      int t = ks * 4 + s;
      bf16x8 a = *(const bf16x8*)&Al[t * 512 + lane * 8];
      bf16x8 b = *(const bf16x8*)&Bl[(t * 4 + cg) * 512 + lane * 8];
      acc = __builtin_amdgcn_mfma_f32_16x16x32_bf16(a, b, acc, 0, 0, 0);
    }
#pragma unroll
    for (int q = 0; q < 4; ++q)
      red0[ks][cg][(lane >> 4) * 4 + q][lane & 15] = acc[q];
  }
  __syncthreads();
  {  // combine 4 k-segments, write t1T (column-half B-tiles)
    int r = wave, c = lane;
    float v = red0[0][c >> 4][r][c & 15] + red0[1][c >> 4][r][c & 15] +
              red0[2][c >> 4][r][c & 15] + red0[3][c >> 4][r][c & 15];
    t1T[bidx(i0 + r, c)] = f2bf(v);
  }
}

// ---- k_layer: y = adj@T via MFMA; quarter-dbuf gl_lds staging, 96 blocks ----
// MODE 0: x = relu(y+b);          outA = x@Wn_top (bf16), outBT = x@Wn_bot
// MODE 1: x = elu(Ain*deg+y+b);   outA/outBT as above
// MODE 2: x = Ain*deg+y+b;        out = log_softmax(x)
template <int MODE>
__global__ __launch_bounds__(NT, 4) void k_layer(
    const u16* __restrict__ adjT, const u16* __restrict__ TT,
    const u16* __restrict__ Ain, const float* __restrict__ deg,
    const float* __restrict__ bias, const float* __restrict__ Wn,
    u16* __restrict__ outA, u16* __restrict__ outBT,
    float* __restrict__ out) {
  // LDS union (bytes): staging [16 waves][6144] @0, red8 @98304 (34816),
  // WnB @133120 (16384), xA @149504 (2048), xloc @151552 (4160) -> 155712 B
  __shared__ __attribute__((aligned(16))) char LB[155712];
  float* red8 = (float*)(LB + 98304);  // [8][4][16][17]
  u16*   WnB  = (u16*)(LB + 133120);   // 16 tiles x 512 u16
  u16*   xA   = (u16*)(LB + 149504);   // x as A-tiles [2][512]
  float* xloc = (float*)(LB + 151552); // [16][65]

  const int tid = threadIdx.x, lane = tid & 63, wave = tid >> 6;
  const int i0 = blockIdx.x * RPB;

  // adj A-fragments: 3 coalesced b128 loads
  const u16* ja = adjT + (size_t)blockIdx.x * (KST * 512);
  bf16x8 afr[3];
#pragma unroll
  for (int s = 0; s < 3; ++s)
    afr[s] = *(const bf16x8*)(ja + (wave * 3 + s) * 512 + lane * 8);

  if (MODE < 2) pack_wnb(WnB, Wn, tid);
  float dg = 0.f;
  if (MODE >= 1) dg = deg[i0 + wave];

  // quarter-dbuf staging: quarter q = col-group q, 3 tiles of 1KB.
  char* const regA = LB + wave * 6144;
  char* const regB = regA + 3072;
  const int kb = wave * 3;
  const char* tb = (const char*)TT + (size_t)lane * 16;

  f32x4 acc[4] = {};
#pragma unroll
  for (int s = 0; s < 3; ++s)
    gl_lds16(tb + (size_t)((kb + s) * 2 + 0) * 1024, regA + s * 1024);
#pragma unroll
  for (int s = 0; s < 3; ++s)
    gl_lds16(tb + (size_t)((kb + s) * 2 + 1) * 1024, regB + s * 1024);

#pragma unroll
  for (int cg = 0; cg < 4; ++cg) {
    if (cg < 3) asm volatile("s_waitcnt vmcnt(3)" ::: "memory");
    else        asm volatile("s_waitcnt vmcnt(0)" ::: "memory");
    __builtin_amdgcn_sched_barrier(0);
    char* reg = (cg & 1) ? regB : regA;
    bf16x8 b0 = *(const bf16x8*)(reg);
    bf16x8 b1 = *(const bf16x8*)(reg + 1024);
    bf16x8 b2 = *(const bf16x8*)(reg + 2048);
    asm volatile("s_waitcnt lgkmcnt(0)" ::: "memory");
    __builtin_amdgcn_sched_barrier(0);
    if (cg < 2) {  // refill just-consumed region with quarter cg+2
      int q = cg + 2;
#pragma unroll
      for (int s = 0; s < 3; ++s)
        gl_lds16(tb + (size_t)((q >> 1) * 96 + (kb + s) * 2 + (q & 1)) * 1024,
                 reg + s * 1024);
    }
    acc[cg] = __builtin_amdgcn_mfma_f32_16x16x32_bf16(afr[0], b0, acc[cg], 0, 0, 0);
    acc[cg] = __builtin_amdgcn_mfma_f32_16x16x32_bf16(afr[1], b1, acc[cg], 0, 0, 0);
    acc[cg] = __builtin_amdgcn_mfma_f32_16x16x32_bf16(afr[2], b2, acc[cg], 0, 0, 0);
  }

  // 8-wave reduction tree (padded stride 17)
  if (wave < 8) {
#pragma unroll
    for (int cg = 0; cg < 4; ++cg)
#pragma unroll
      for (int q = 0; q < 4; ++q)
        red8[((wave * 4 + cg) * 16 + ((lane >> 4) * 4 + q)) * 17 +
             (lane & 15)] = acc[cg][q];
  }
  __syncthreads();
  if (wave >= 8) {
#pragma unroll
    for (int cg = 0; cg < 4; ++cg)
#pragma unroll
      for (int q = 0; q < 4; ++q)
        red8[(((wave - 8) * 4 + cg) * 16 + ((lane >> 4) * 4 + q)) * 17 +
             (lane & 15)] += acc[cg][q];
  }
  __syncthreads();

  {  // combine 8 segments + bias + deg term + activation
    float v = bias[lane];
#pragma unroll
    for (int s = 0; s < 8; ++s)
      v += red8[((s * 4 + (lane >> 4)) * 16 + wave) * 17 + (lane & 15)];
    if (MODE >= 1) v += bf2f(Ain[(size_t)(i0 + wave) * HH + lane]) * dg;
    if (MODE == 0) v = fmaxf(v, 0.f);
    if (MODE == 1) v = v > 0.f ? v : expm1f(v);
    xloc[wave * 65 + lane] = v;
    if (MODE < 2)
      xA[(lane >> 5) * 512 + ((lane & 31) >> 3) * 128 + wave * 8 +
         (lane & 7)] = f2bf(v);
  }
  __syncthreads();

  if (MODE < 2) {
    // epilogue: [outA | outBT] = x @ [Wn_top | Wn_bot] via MFMA (8 waves)
    if (wave < 8) {
      f32x4 a2 = {};
#pragma unroll
      for (int s = 0; s < 2; ++s) {
        bf16x8 a = *(const bf16x8*)&xA[s * 512 + lane * 8];
        bf16x8 b = *(const bf16x8*)&WnB[(s * 8 + wave) * 512 + lane * 8];
        a2 = __builtin_amdgcn_mfma_f32_16x16x32_bf16(a, b, a2, 0, 0, 0);
      }
      int row = (lane >> 4) * 4, colg = lane & 15;
      if (wave < 4) {
        int c = wave * 16 + colg;
#pragma unroll
        for (int q = 0; q < 4; ++q)
          outA[(size_t)(i0 + row + q) * HH + c] = f2bf(a2[q]);
      } else {
        int c = (wave - 4) * 16 + colg;
        u16x4 v;
#pragma unroll
        for (int q = 0; q < 4; ++q) v[q] = f2bf(a2[q]);
        *(u16x4*)&outBT[bidx(i0 + row, c)] = v;  // 4 consecutive k slots
      }
    }
  } else {
    // log_softmax: wave = row
    float v = xloc[wave * 65 + lane];
    float m = v;
#pragma unroll
    for (int off = 32; off; off >>= 1) m = fmaxf(m, __shfl_xor(m, off, 64));
    float e = expf(v - m);
    float ssum = e;
#pragma unroll
    for (int off = 32; off; off >>= 1) ssum += __shfl_xor(ssum, off, 64);
    out[(size_t)(i0 + wave) * HH + lane] = v - m - logf(ssum);
  }
}

extern "C" void kernel_launch(void* const* d_in, const int* in_sizes, int n_in,
                              void* d_out, int out_size, void* d_ws,
                              size_t ws_size, hipStream_t stream) {
  const float* x   = (const float*)d_in[0];
  const float* adj = (const float*)d_in[2];  // adj1; d_in[1]/[3] are dead
  const float* W1  = (const float*)d_in[4];
  const float* b1  = (const float*)d_in[5];
  const float* W2  = (const float*)d_in[6];
  const float* b2  = (const float*)d_in[7];
  const float* W3  = (const float*)d_in[8];
  const float* b3  = (const float*)d_in[9];
  float* out = (float*)d_out;

  char* ws = (char*)d_ws;
  u16* adjT = (u16*)ws;                   // 4,718,592 B
  u16* t1T  = (u16*)(ws + 4718592);       // 196,608 B each (2 x 96KB halves)
  u16* B2T  = (u16*)(ws + 4915200);
  u16* B3T  = (u16*)(ws + 5111808);
  u16* A2   = (u16*)(ws + 5308416);       // 196,608 B each (bf16 now)
  u16* A3   = (u16*)(ws + 5505024);
  float* dg = (float*)(ws + 5701632);     // 6,144 B

  k_pre<<<NB, NT, 0, stream>>>(x, adj, W1, adjT, t1T, dg);
  k_layer<0><<<NB, NT, 0, stream>>>(adjT, t1T, nullptr, nullptr, b1, W2, A2,
                                    B2T, nullptr);
  k_layer<1><<<NB, NT, 0, stream>>>(adjT, B2T, A2, dg, b2, W3, A3, B3T,
                                    nullptr);
  k_layer<2><<<NB, NT, 0, stream>>>(adjT, B3T, A3, dg, b3, nullptr, nullptr,
                                    nullptr, out);
}